// Round 9
// baseline (907.919 us; speedup 1.0000x reference)
//
#include <hip/hip_runtime.h>
#include <hip/hip_bf16.h>

// Problem dims
#define Bn 2
#define Tn 4
#define NCc 3
#define NKc 16
#define Hc 180
#define Wc 320
#define HWc (Hc * Wc)          // 57600
#define NPIX (Bn * HWc)        // 115200
#define CIN_LSTM 19            // NC + NK
#define GATES 64               // 4*NK
#define CIN_D 64               // T*NK
#define TAPS_L (CIN_LSTM * 9)  // 171
#define TAPS_D (CIN_D * 9)     // 576
#define TAPS_O (NKc * 9)       // 144

typedef __hip_bfloat16 bf16;

__device__ __forceinline__ float getv(const float* p, long i) { return p[i]; }
__device__ __forceinline__ float getv(const bf16* p, long i) {
    unsigned int u = ((unsigned int)((const unsigned short*)p)[i]) << 16;
    return __uint_as_float(u);
}
__device__ __forceinline__ void putv(float* p, long i, float v) { p[i] = v; }
__device__ __forceinline__ void putv(bf16* p, long i, float v) { p[i] = __float2bfloat16(v); }
__device__ __forceinline__ float sigm(float x) { return 1.0f / (1.0f + __expf(-x)); }
__device__ __forceinline__ float tanh_(float x) { return 1.0f - 2.0f / (__expf(2.0f * x) + 1.0f); }

__device__ __forceinline__ void load4(const float* row, int x0, float* d) {
    const float4 v = *(const float4*)(row + x0);
    d[0] = v.x; d[1] = v.y; d[2] = v.z; d[3] = v.w;
}
__device__ __forceinline__ void load4(const bf16* row, int x0, float* d) {
    ushort4 u = *(const ushort4*)((const unsigned short*)row + x0);
    d[0] = __uint_as_float(((unsigned int)u.x) << 16);
    d[1] = __uint_as_float(((unsigned int)u.y) << 16);
    d[2] = __uint_as_float(((unsigned int)u.z) << 16);
    d[3] = __uint_as_float(((unsigned int)u.w) << 16);
}

// Hoisted 3-row window load: xs[ky][0..5] for rows y-1..y+1 (zeros outside).
template <typename S>
__device__ __forceinline__ void load_rows(
    const S* __restrict__ plane, int y, int x0, float (&xs)[3][6])
{
#pragma unroll
    for (int ky = 0; ky < 3; ky++) {
        int yy = y + ky - 1;
        if (yy >= 0 && yy < Hc) {
            const S* row = plane + (long)yy * Wc;
            xs[ky][0] = (x0 > 0) ? getv(row, x0 - 1) : 0.0f;
            load4(row, x0, &xs[ky][1]);
            xs[ky][5] = (x0 + 4 < Wc) ? getv(row, x0 + 4) : 0.0f;
        } else {
#pragma unroll
            for (int j = 0; j < 6; j++) xs[ky][j] = 0.0f;
        }
    }
}

// ---------------------------------------------------------------------------
// Dtype probe (bf16 vs float32 inputs) -> flag in d_ws.
// ---------------------------------------------------------------------------
__global__ void __launch_bounds__(256) k_detect(const void* lstm_w_raw, int* flag)
{
    __shared__ int bad;
    if (threadIdx.x == 0) bad = 0;
    __syncthreads();
    const unsigned short* u = (const unsigned short*)lstm_w_raw;
    int local = 0;
    for (int i = threadIdx.x; i < GATES * TAPS_L; i += 256) {
        unsigned int f32 = ((unsigned int)u[i]) << 16;
        float v = __uint_as_float(f32);
        if (!(fabsf(v) <= 64.0f)) local = 1;
    }
    if (local) atomicOr(&bad, 1);
    __syncthreads();
    if (threadIdx.x == 0) flag[0] = bad ? 0 : 1;
}

// ---------------------------------------------------------------------------
// ConvLSTM step v3 (ROUND-9): weights staged in TWO cin-chunks (10 + 9) ->
// LDS 23.0 KB -> ~6 blocks/CU (was 43.8 KB, 3). Rows hoisted per cin.
// Block = 256 thr = 16 kc x 16 lanes(4px); grid 1800.
// ---------------------------------------------------------------------------
template <typename S>
__device__ __forceinline__ void conv_plane3(
    const S* __restrict__ plane, int wcin, int y, int x0, int kc,
    const float* __restrict__ sw, float (&acc)[4][4])
{
    float xs[3][6];
    load_rows(plane, y, x0, xs);
#pragma unroll
    for (int ky = 0; ky < 3; ky++) {
#pragma unroll
        for (int kx = 0; kx < 3; kx++) {
            int tap = wcin * 9 + ky * 3 + kx;
            const float4 wq = *(const float4*)&sw[(tap * 16 + kc) * 4];
#pragma unroll
            for (int px = 0; px < 4; px++) {
                float v = xs[ky][px + kx];
                acc[0][px] += wq.x * v;
                acc[1][px] += wq.y * v;
                acc[2][px] += wq.z * v;
                acc[3][px] += wq.w * v;
            }
        }
    }
}

template <typename T>
__device__ __forceinline__ void stage_lstm_chunk(
    const T* __restrict__ lstm_w, int base, int ncin, float* sw)
{
    int n = ncin * 9;
    for (int i = threadIdx.x; i < GATES * n; i += 256) {
        int co = i / n, tl = i - co * n;
        int kc = co & 15, g = co >> 4;
        sw[(tl * 16 + kc) * 4 + g] = getv(lstm_w, (long)co * TAPS_L + base * 9 + tl);
    }
}

template <typename T>
__device__ __forceinline__ void lstm3_body(
    const T* __restrict__ X, const T* __restrict__ lstm_w, const T* __restrict__ lstm_b,
    const T* __restrict__ Wci, const T* __restrict__ Wcf, const T* __restrict__ Wco,
    float* __restrict__ c_buf, float* __restrict__ xcat, int t,
    float* sw, float* sb)
{
    stage_lstm_chunk(lstm_w, 0, 10, sw);   // cin 0..9
    if (threadIdx.x < GATES) sb[threadIdx.x] = getv(lstm_b, threadIdx.x);
    __syncthreads();

    int blk = blockIdx.x;
    int seg = blk % 5; int rem = blk / 5;
    int y = rem % Hc; int b = rem / Hc;
    int kc = threadIdx.x >> 4, pl = threadIdx.x & 15;
    int x0 = seg * 64 + pl * 4;

    float acc[4][4];
#pragma unroll
    for (int px = 0; px < 4; px++) {
        acc[0][px] = sb[kc];
        acc[1][px] = sb[16 + kc];
        acc[2][px] = sb[32 + kc];
        acc[3][px] = sb[48 + kc];
    }

    const T* xt = X + (long)(b * Tn + t) * NCc * HWc;
    const float* hp = xcat + ((long)b * CIN_D + (t > 0 ? (t - 1) * NKc : 0)) * HWc;

#pragma unroll
    for (int cin = 0; cin < NCc; cin++)
        conv_plane3(xt + (long)cin * HWc, cin, y, x0, kc, sw, acc);
    if (t > 0) {
#pragma unroll 1
        for (int cin = 3; cin < 10; cin++)
            conv_plane3(hp + (long)(cin - 3) * HWc, cin, y, x0, kc, sw, acc);
    }

    __syncthreads();
    stage_lstm_chunk(lstm_w, 10, 9, sw);   // cin 10..18
    __syncthreads();

    if (t > 0) {
#pragma unroll 1
        for (int cin = 10; cin < CIN_LSTM; cin++)
            conv_plane3(hp + (long)(cin - 3) * HWc, cin - 10, y, x0, kc, sw, acc);
    }

    long pbase = (long)y * Wc + x0;
    float* cb = c_buf + (long)(b * NKc + kc) * HWc + pbase;
    float cprev[4];
    if (t > 0) {
        const float4 cv = *(const float4*)cb;
        cprev[0] = cv.x; cprev[1] = cv.y; cprev[2] = cv.z; cprev[3] = cv.w;
    } else {
        cprev[0] = cprev[1] = cprev[2] = cprev[3] = 0.0f;
    }
    float wci[4], wcf[4], wco[4];
    load4(Wci + (long)kc * HWc + pbase, 0, wci);
    load4(Wcf + (long)kc * HWc + pbase, 0, wcf);
    load4(Wco + (long)kc * HWc + pbase, 0, wco);

    float cn4[4], h4[4];
#pragma unroll
    for (int px = 0; px < 4; px++) {
        float ii = sigm(acc[0][px] + wci[px] * cprev[px]);
        float ff = sigm(acc[1][px] + wcf[px] * cprev[px]);
        float cn = ff * cprev[px] + ii * tanh_(acc[2][px]);
        float oo = sigm(acc[3][px] + wco[px] * cn);
        cn4[px] = cn; h4[px] = oo * tanh_(cn);
    }
    *(float4*)cb = make_float4(cn4[0], cn4[1], cn4[2], cn4[3]);
    *(float4*)(xcat + ((long)b * CIN_D + t * NKc + kc) * HWc + pbase) =
        make_float4(h4[0], h4[1], h4[2], h4[3]);
}

__global__ void __launch_bounds__(256) k_lstm2(
    const void* X, const void* lstm_w, const void* lstm_b,
    const void* Wci, const void* Wcf, const void* Wco,
    const int* __restrict__ flag,
    float* c_buf, float* xcat, int t)
{
    __shared__ float sw[10 * 9 * GATES];  // 23.0 KB (chunk of <=10 cins)
    __shared__ float sb[GATES];
    if (flag[0])
        lstm3_body<bf16>((const bf16*)X, (const bf16*)lstm_w, (const bf16*)lstm_b,
                         (const bf16*)Wci, (const bf16*)Wcf, (const bf16*)Wco,
                         c_buf, xcat, t, sw, sb);
    else
        lstm3_body<float>((const float*)X, (const float*)lstm_w, (const float*)lstm_b,
                          (const float*)Wci, (const float*)Wcf, (const float*)Wco,
                          c_buf, xcat, t, sw, sb);
}

// ---------------------------------------------------------------------------
// offmod v5 (ROUND-9): R8 og-wave structure + hoisted 3-row loads per cin
// (9 loads in flight before the 9-tap FMA block).
// ---------------------------------------------------------------------------
template <typename T>
__device__ __forceinline__ void offmod5_body(
    const float* __restrict__ xcat,
    const T* __restrict__ off_w, const T* __restrict__ off_b,
    const T* __restrict__ mod_w, const T* __restrict__ mod_b,
    float* __restrict__ offbuf, float* __restrict__ maskbuf,
    float* sw, float* sb)
{
    for (int i = threadIdx.x; i < TAPS_D * 28; i += 256) {
        int tap = i / 28, o = i - tap * 28;
        float v = 0.0f;
        if (o < 18) v = getv(off_w, (long)o * TAPS_D + tap);
        else if (o < 27) v = getv(mod_w, (long)(o - 18) * TAPS_D + tap);
        sw[tap * 28 + o] = v;
    }
    if (threadIdx.x < 18) sb[threadIdx.x] = getv(off_b, threadIdx.x);
    else if (threadIdx.x < 27) sb[threadIdx.x] = getv(mod_b, threadIdx.x - 18);
    else if (threadIdx.x < 28) sb[threadIdx.x] = 0.0f;
    __syncthreads();

    int og = threadIdx.x >> 6, lane = threadIdx.x & 63;
    int obase = og * 8;
    int nout = (og < 3) ? 8 : 3;
    long p0 = ((long)blockIdx.x * 64 + lane) * 4;
    int b = (int)(p0 / HWc);
    int p = (int)(p0 - (long)b * HWc);
    int y = p / Wc, x0 = p - (p / Wc) * Wc;

    float acc[8][4];
#pragma unroll
    for (int j = 0; j < 8; j++) {
        float bv = sb[min(obase + j, 27)];
#pragma unroll
        for (int px = 0; px < 4; px++) acc[j][px] = bv;
    }

    const float* xb = xcat + (long)b * CIN_D * HWc;
#pragma unroll 1
    for (int cin = 0; cin < CIN_D; cin++) {
        float xs[3][6];
        load_rows(xb + (long)cin * HWc, y, x0, xs);
#pragma unroll
        for (int ky = 0; ky < 3; ky++) {
#pragma unroll
            for (int kx = 0; kx < 3; kx++) {
                int tap = (cin * 3 + ky) * 3 + kx;
                const float* wp = &sw[tap * 28 + obase];
                const float4 w0 = *(const float4*)wp;
#pragma unroll
                for (int px = 0; px < 4; px++) {
                    float v = xs[ky][px + kx];
                    acc[0][px] += w0.x * v;
                    acc[1][px] += w0.y * v;
                    acc[2][px] += w0.z * v;
                    acc[3][px] += w0.w * v;
                }
                if (og < 3) {
                    const float4 w1 = *(const float4*)(wp + 4);
#pragma unroll
                    for (int px = 0; px < 4; px++) {
                        float v = xs[ky][px + kx];
                        acc[4][px] += w1.x * v;
                        acc[5][px] += w1.y * v;
                        acc[6][px] += w1.z * v;
                        acc[7][px] += w1.w * v;
                    }
                }
            }
        }
    }

    long pbase = (long)y * Wc + x0;
#pragma unroll
    for (int j = 0; j < 8; j++) {
        if (j >= nout) break;
        int o = obase + j;
        if (o < 18) {
            *(float4*)(offbuf + ((long)b * 18 + o) * HWc + pbase) =
                make_float4(acc[j][0], acc[j][1], acc[j][2], acc[j][3]);
        } else {
            *(float4*)(maskbuf + ((long)b * 9 + (o - 18)) * HWc + pbase) =
                make_float4(2.0f * sigm(acc[j][0]), 2.0f * sigm(acc[j][1]),
                            2.0f * sigm(acc[j][2]), 2.0f * sigm(acc[j][3]));
        }
    }
}

__global__ void __launch_bounds__(256) k_offmod(
    const float* xcat, const void* off_w, const void* off_b,
    const void* mod_w, const void* mod_b, const int* __restrict__ flag,
    float* offbuf, float* maskbuf)
{
    __shared__ float sw[TAPS_D * 28];  // 64.5 KB
    __shared__ float sb[28];
    if (flag[0])
        offmod5_body<bf16>(xcat, (const bf16*)off_w, (const bf16*)off_b,
                           (const bf16*)mod_w, (const bf16*)mod_b, offbuf, maskbuf, sw, sb);
    else
        offmod5_body<float>(xcat, (const float*)off_w, (const float*)off_b,
                            (const float*)mod_w, (const float*)mod_b, offbuf, maskbuf, sw, sb);
}

// ---------------------------------------------------------------------------
// Deformable conv (round-3 body, unchanged).
// ---------------------------------------------------------------------------
template <typename T>
__device__ __forceinline__ void deform_body(
    const float* __restrict__ xcat, const float* __restrict__ offbuf,
    const float* __restrict__ maskbuf,
    const T* __restrict__ def_w, const T* __restrict__ def_b,
    float* __restrict__ dcout, float* sw, float* sb)
{
    for (int i = threadIdx.x; i < NKc * TAPS_D; i += 256) {
        int co = i / TAPS_D;
        int tap = i - co * TAPS_D;
        sw[tap * NKc + co] = getv(def_w, i);
    }
    if (threadIdx.x < NKc) sb[threadIdx.x] = getv(def_b, threadIdx.x);
    __syncthreads();

    int idx = blockIdx.x * 256 + threadIdx.x;
    int b = idx / HWc;
    int p = idx - b * HWc;
    int y = p / Wc, x = p - (p / Wc) * Wc;

    float acc[NKc];
#pragma unroll
    for (int i = 0; i < NKc; i++) acc[i] = 0.0f;

    const float* xb = xcat + (long)b * CIN_D * HWc;

#pragma unroll 1
    for (int k = 0; k < 9; k++) {
        int ky = k / 3, kx = k - (k / 3) * 3;
        float dy = offbuf[((long)b * 18 + 2 * k) * HWc + p];
        float dx = offbuf[((long)b * 18 + 2 * k + 1) * HWc + p];
        float m = maskbuf[((long)b * 9 + k) * HWc + p];
        float py = (float)(y - 1 + ky) + dy;
        float px = (float)(x - 1 + kx) + dx;
        float y0f = floorf(py), x0f = floorf(px);
        int y0 = (int)y0f, x0 = (int)x0f;
        float wy1 = py - y0f, wx1 = px - x0f;
        float w00 = (1.0f - wy1) * (1.0f - wx1) * m;
        float w01 = (1.0f - wy1) * wx1 * m;
        float w10 = wy1 * (1.0f - wx1) * m;
        float w11 = wy1 * wx1 * m;
        bool vy0 = (y0 >= 0) && (y0 < Hc);
        bool vy1 = (y0 + 1 >= 0) && (y0 + 1 < Hc);
        bool vx0 = (x0 >= 0) && (x0 < Wc);
        bool vx1 = (x0 + 1 >= 0) && (x0 + 1 < Wc);
        if (!(vy0 && vx0)) w00 = 0.0f;
        if (!(vy0 && vx1)) w01 = 0.0f;
        if (!(vy1 && vx0)) w10 = 0.0f;
        if (!(vy1 && vx1)) w11 = 0.0f;
        int yc0 = min(max(y0, 0), Hc - 1);
        int yc1 = min(max(y0 + 1, 0), Hc - 1);
        int xc0 = min(max(x0, 0), Wc - 1);
        int xc1 = min(max(x0 + 1, 0), Wc - 1);
        int i00 = yc0 * Wc + xc0, i01 = yc0 * Wc + xc1;
        int i10 = yc1 * Wc + xc0, i11 = yc1 * Wc + xc1;

#pragma unroll 4
        for (int cin = 0; cin < CIN_D; cin++) {
            const float* xc = xb + (long)cin * HWc;
            float s = w00 * xc[i00] + w01 * xc[i01] + w10 * xc[i10] + w11 * xc[i11];
            const float* wrow = &sw[(cin * 9 + k) * NKc];
#pragma unroll
            for (int co = 0; co < NKc; co++) acc[co] += wrow[co] * s;
        }
    }

#pragma unroll
    for (int co = 0; co < NKc; co++)
        dcout[((long)b * NKc + co) * HWc + p] = acc[co] + sb[co];
}

__global__ void __launch_bounds__(256) k_deform(
    const float* xcat, const float* offbuf, const float* maskbuf,
    const void* def_w, const void* def_b, const int* __restrict__ flag,
    float* dcout)
{
    __shared__ float sw[TAPS_D * NKc];  // 36.9 KB
    __shared__ float sb[NKc];
    if (flag[0])
        deform_body<bf16>(xcat, offbuf, maskbuf, (const bf16*)def_w, (const bf16*)def_b,
                          dcout, sw, sb);
    else
        deform_body<float>(xcat, offbuf, maskbuf, (const float*)def_w, (const float*)def_b,
                           dcout, sw, sb);
}

// ---------------------------------------------------------------------------
// outconv v4 (ROUND-9): R8 og-wave structure + hoisted 3-row loads per cin.
// ---------------------------------------------------------------------------
template <typename T>
__device__ __forceinline__ void outconv5_body(
    const float* __restrict__ dcout, const T* __restrict__ out_w,
    const T* __restrict__ out_b, T* __restrict__ out, float* sw, float* sb)
{
    for (int i = threadIdx.x; i < 48 * TAPS_O; i += 256) {
        int co = i / TAPS_O;
        int tap = i - co * TAPS_O;
        sw[tap * 48 + co] = getv(out_w, i);
    }
    if (threadIdx.x < 48) sb[threadIdx.x] = getv(out_b, threadIdx.x);
    __syncthreads();

    int og = threadIdx.x >> 6, lane = threadIdx.x & 63;
    int obase = og * 12;
    long p0 = ((long)blockIdx.x * 64 + lane) * 4;
    int b = (int)(p0 / HWc);
    int p = (int)(p0 - (long)b * HWc);
    int y = p / Wc, x0 = p - (p / Wc) * Wc;

    float acc[12][4];
#pragma unroll
    for (int j = 0; j < 12; j++) {
        float bv = sb[obase + j];
#pragma unroll
        for (int px = 0; px < 4; px++) acc[j][px] = bv;
    }

    const float* xb = dcout + (long)b * NKc * HWc;
#pragma unroll 1
    for (int cin = 0; cin < NKc; cin++) {
        float xs[3][6];
        load_rows(xb + (long)cin * HWc, y, x0, xs);
#pragma unroll
        for (int ky = 0; ky < 3; ky++) {
#pragma unroll
            for (int kx = 0; kx < 3; kx++) {
                int tap = (cin * 3 + ky) * 3 + kx;
                const float* wp = &sw[tap * 48 + obase];
                const float4 w0 = *(const float4*)wp;
                const float4 w1 = *(const float4*)(wp + 4);
                const float4 w2 = *(const float4*)(wp + 8);
#pragma unroll
                for (int px = 0; px < 4; px++) {
                    float v = xs[ky][px + kx];
                    acc[0][px] += w0.x * v;  acc[1][px] += w0.y * v;
                    acc[2][px] += w0.z * v;  acc[3][px] += w0.w * v;
                    acc[4][px] += w1.x * v;  acc[5][px] += w1.y * v;
                    acc[6][px] += w1.z * v;  acc[7][px] += w1.w * v;
                    acc[8][px] += w2.x * v;  acc[9][px] += w2.y * v;
                    acc[10][px] += w2.z * v; acc[11][px] += w2.w * v;
                }
            }
        }
    }

#pragma unroll
    for (int j = 0; j < 12; j++) {
        int co = obase + j;
        int cc = co >> 4;
        int r = co & 15;
        int ii = r >> 2, jj = r & 3;
        long ob = (((long)b * 3 + cc) * (Hc * 4) + (y * 4 + ii)) * (long)(Wc * 4);
#pragma unroll
        for (int px = 0; px < 4; px++) {
            float v = fminf(fmaxf(acc[j][px], 0.0f), 255.0f);
            putv(out, ob + (x0 + px) * 4 + jj, v);
        }
    }
}

__global__ void __launch_bounds__(256) k_outconv(
    const float* dcout, const void* out_w, const void* out_b,
    const int* __restrict__ flag, void* out)
{
    __shared__ float sw[TAPS_O * 48];  // 27.6 KB
    __shared__ float sb[48];
    if (flag[0])
        outconv5_body<bf16>(dcout, (const bf16*)out_w, (const bf16*)out_b, (bf16*)out, sw, sb);
    else
        outconv5_body<float>(dcout, (const float*)out_w, (const float*)out_b, (float*)out, sw, sb);
}

extern "C" void kernel_launch(void* const* d_in, const int* in_sizes, int n_in,
                              void* d_out, int out_size, void* d_ws, size_t ws_size,
                              hipStream_t stream) {
    const void* X      = d_in[0];
    const void* lstm_w = d_in[1];
    const void* lstm_b = d_in[2];
    const void* Wci    = d_in[3];
    const void* Wcf    = d_in[4];
    const void* Wco    = d_in[5];
    const void* off_w  = d_in[6];
    const void* off_b  = d_in[7];
    const void* mod_w  = d_in[8];
    const void* mod_b  = d_in[9];
    const void* def_w  = d_in[10];
    const void* def_b  = d_in[11];
    const void* out_w  = d_in[12];
    const void* out_b  = d_in[13];

    int* flag = (int*)d_ws;
    float* W = (float*)d_ws + 64;
    size_t o = 0;
    float* c_buf   = W + o; o += (size_t)Bn * NKc * HWc;
    float* xcat    = W + o; o += (size_t)Bn * CIN_D * HWc;
    float* offbuf  = W + o; o += (size_t)Bn * 18 * HWc;
    float* maskbuf = W + o; o += (size_t)Bn * 9 * HWc;
    float* dcout   = W + o; o += (size_t)Bn * NKc * HWc;

    dim3 blk(256);
    dim3 gridP(NPIX / 256);          // 450
    dim3 gridL(Bn * Hc * 5);         // 1800
    dim3 gridC(NPIX / 4 / 64);       // 450

    k_detect<<<1, blk, 0, stream>>>(lstm_w, flag);
    for (int t = 0; t < Tn; t++) {
        k_lstm2<<<gridL, blk, 0, stream>>>(X, lstm_w, lstm_b, Wci, Wcf, Wco,
                                           flag, c_buf, xcat, t);
    }
    k_offmod<<<gridC, blk, 0, stream>>>(xcat, off_w, off_b, mod_w, mod_b, flag,
                                        offbuf, maskbuf);
    k_deform<<<gridP, blk, 0, stream>>>(xcat, offbuf, maskbuf, def_w, def_b, flag, dcout);
    k_outconv<<<gridC, blk, 0, stream>>>(dcout, out_w, out_b, flag, d_out);
}

// Round 10
// 800.587 us; speedup vs baseline: 1.1341x; 1.1341x over previous
//
#include <hip/hip_runtime.h>
#include <hip/hip_bf16.h>

// Problem dims
#define Bn 2
#define Tn 4
#define NCc 3
#define NKc 16
#define Hc 180
#define Wc 320
#define HWc (Hc * Wc)          // 57600
#define NPIX (Bn * HWc)        // 115200
#define CIN_LSTM 19            // NC + NK
#define GATES 64               // 4*NK
#define CIN_D 64               // T*NK
#define TAPS_L (CIN_LSTM * 9)  // 171
#define TAPS_D (CIN_D * 9)     // 576
#define TAPS_O (NKc * 9)       // 144

typedef __hip_bfloat16 bf16;

__device__ __forceinline__ float getv(const float* p, long i) { return p[i]; }
__device__ __forceinline__ float getv(const bf16* p, long i) {
    unsigned int u = ((unsigned int)((const unsigned short*)p)[i]) << 16;
    return __uint_as_float(u);
}
__device__ __forceinline__ void putv(float* p, long i, float v) { p[i] = v; }
__device__ __forceinline__ void putv(bf16* p, long i, float v) { p[i] = __float2bfloat16(v); }
__device__ __forceinline__ float sigm(float x) { return 1.0f / (1.0f + __expf(-x)); }
__device__ __forceinline__ float tanh_(float x) { return 1.0f - 2.0f / (__expf(2.0f * x) + 1.0f); }

__device__ __forceinline__ void load4(const float* row, int x0, float* d) {
    const float4 v = *(const float4*)(row + x0);
    d[0] = v.x; d[1] = v.y; d[2] = v.z; d[3] = v.w;
}
__device__ __forceinline__ void load4(const bf16* row, int x0, float* d) {
    ushort4 u = *(const ushort4*)((const unsigned short*)row + x0);
    d[0] = __uint_as_float(((unsigned int)u.x) << 16);
    d[1] = __uint_as_float(((unsigned int)u.y) << 16);
    d[2] = __uint_as_float(((unsigned int)u.z) << 16);
    d[3] = __uint_as_float(((unsigned int)u.w) << 16);
}

// Hoisted 3-row window load (used by outconv): xs[ky][0..5], zeros outside.
template <typename S>
__device__ __forceinline__ void load_rows(
    const S* __restrict__ plane, int y, int x0, float (&xs)[3][6])
{
#pragma unroll
    for (int ky = 0; ky < 3; ky++) {
        int yy = y + ky - 1;
        if (yy >= 0 && yy < Hc) {
            const S* row = plane + (long)yy * Wc;
            xs[ky][0] = (x0 > 0) ? getv(row, x0 - 1) : 0.0f;
            load4(row, x0, &xs[ky][1]);
            xs[ky][5] = (x0 + 4 < Wc) ? getv(row, x0 + 4) : 0.0f;
        } else {
#pragma unroll
            for (int j = 0; j < 6; j++) xs[ky][j] = 0.0f;
        }
    }
}

// ---------------------------------------------------------------------------
// Dtype probe (bf16 vs float32 inputs) -> flag in d_ws.
// ---------------------------------------------------------------------------
__global__ void __launch_bounds__(256) k_detect(const void* lstm_w_raw, int* flag)
{
    __shared__ int bad;
    if (threadIdx.x == 0) bad = 0;
    __syncthreads();
    const unsigned short* u = (const unsigned short*)lstm_w_raw;
    int local = 0;
    for (int i = threadIdx.x; i < GATES * TAPS_L; i += 256) {
        unsigned int f32 = ((unsigned int)u[i]) << 16;
        float v = __uint_as_float(f32);
        if (!(fabsf(v) <= 64.0f)) local = 1;
    }
    if (local) atomicOr(&bad, 1);
    __syncthreads();
    if (threadIdx.x == 0) flag[0] = bad ? 0 : 1;
}

// ---------------------------------------------------------------------------
// ConvLSTM step — REVERTED to the proven R8 single-stage structure.
// Block = 256 thr = 16 kc x 16 lanes(4px). Weights LDS fp32 [tap][kc][gate].
// ---------------------------------------------------------------------------
template <typename S>
__device__ __forceinline__ void conv_plane(
    const S* __restrict__ src, int cin, int y, int x0, int kc,
    const float* __restrict__ sw, float (&acc)[4][4])
{
#pragma unroll
    for (int ky = 0; ky < 3; ky++) {
        int yy = y + ky - 1;
        if (yy < 0 || yy >= Hc) continue;
        const S* row = src + (long)yy * Wc;
        float xs[6];
        xs[0] = (x0 > 0) ? getv(row, x0 - 1) : 0.0f;
        load4(row, x0, &xs[1]);
        xs[5] = (x0 + 4 < Wc) ? getv(row, x0 + 4) : 0.0f;
#pragma unroll
        for (int kx = 0; kx < 3; kx++) {
            int tap = (cin * 3 + ky) * 3 + kx;
            const float4 wq = *(const float4*)&sw[(tap * 16 + kc) * 4];
#pragma unroll
            for (int px = 0; px < 4; px++) {
                float v = xs[px + kx];
                acc[0][px] += wq.x * v;
                acc[1][px] += wq.y * v;
                acc[2][px] += wq.z * v;
                acc[3][px] += wq.w * v;
            }
        }
    }
}

template <typename T>
__device__ __forceinline__ void lstm2_body(
    const T* __restrict__ X, const T* __restrict__ lstm_w, const T* __restrict__ lstm_b,
    const T* __restrict__ Wci, const T* __restrict__ Wcf, const T* __restrict__ Wco,
    float* __restrict__ c_buf, float* __restrict__ xcat, int t,
    float* sw, float* sb)
{
    for (int i = threadIdx.x; i < GATES * TAPS_L; i += 256) {
        int co = i / TAPS_L, tap = i - co * TAPS_L;
        int kc = co & 15, g = co >> 4;
        sw[(tap * 16 + kc) * 4 + g] = getv(lstm_w, i);
    }
    if (threadIdx.x < GATES) sb[threadIdx.x] = getv(lstm_b, threadIdx.x);
    __syncthreads();

    int blk = blockIdx.x;
    int seg = blk % 5; int rem = blk / 5;
    int y = rem % Hc; int b = rem / Hc;
    int kc = threadIdx.x >> 4, pl = threadIdx.x & 15;
    int x0 = seg * 64 + pl * 4;

    float acc[4][4];
#pragma unroll
    for (int px = 0; px < 4; px++) {
        acc[0][px] = sb[kc];
        acc[1][px] = sb[16 + kc];
        acc[2][px] = sb[32 + kc];
        acc[3][px] = sb[48 + kc];
    }

    const T* xt = X + (long)(b * Tn + t) * NCc * HWc;
#pragma unroll
    for (int cin = 0; cin < NCc; cin++)
        conv_plane(xt + (long)cin * HWc, cin, y, x0, kc, sw, acc);
    if (t > 0) {
        const float* hp = xcat + ((long)b * CIN_D + (t - 1) * NKc) * HWc;
#pragma unroll 1
        for (int cin = 0; cin < NKc; cin++)
            conv_plane(hp + (long)cin * HWc, cin + NCc, y, x0, kc, sw, acc);
    }

    long pbase = (long)y * Wc + x0;
    float* cb = c_buf + (long)(b * NKc + kc) * HWc + pbase;
    float cprev[4];
    if (t > 0) {
        const float4 cv = *(const float4*)cb;
        cprev[0] = cv.x; cprev[1] = cv.y; cprev[2] = cv.z; cprev[3] = cv.w;
    } else {
        cprev[0] = cprev[1] = cprev[2] = cprev[3] = 0.0f;
    }
    float wci[4], wcf[4], wco[4];
    load4(Wci + (long)kc * HWc + pbase, 0, wci);
    load4(Wcf + (long)kc * HWc + pbase, 0, wcf);
    load4(Wco + (long)kc * HWc + pbase, 0, wco);

    float cn4[4], h4[4];
#pragma unroll
    for (int px = 0; px < 4; px++) {
        float ii = sigm(acc[0][px] + wci[px] * cprev[px]);
        float ff = sigm(acc[1][px] + wcf[px] * cprev[px]);
        float cn = ff * cprev[px] + ii * tanh_(acc[2][px]);
        float oo = sigm(acc[3][px] + wco[px] * cn);
        cn4[px] = cn; h4[px] = oo * tanh_(cn);
    }
    *(float4*)cb = make_float4(cn4[0], cn4[1], cn4[2], cn4[3]);
    *(float4*)(xcat + ((long)b * CIN_D + t * NKc + kc) * HWc + pbase) =
        make_float4(h4[0], h4[1], h4[2], h4[3]);
}

__global__ void __launch_bounds__(256) k_lstm2(
    const void* X, const void* lstm_w, const void* lstm_b,
    const void* Wci, const void* Wcf, const void* Wco,
    const int* __restrict__ flag,
    float* c_buf, float* xcat, int t)
{
    __shared__ float sw[TAPS_L * GATES];  // 43.8 KB
    __shared__ float sb[GATES];
    if (flag[0])
        lstm2_body<bf16>((const bf16*)X, (const bf16*)lstm_w, (const bf16*)lstm_b,
                         (const bf16*)Wci, (const bf16*)Wcf, (const bf16*)Wco,
                         c_buf, xcat, t, sw, sb);
    else
        lstm2_body<float>((const float*)X, (const float*)lstm_w, (const float*)lstm_b,
                          (const float*)Wci, (const float*)Wcf, (const float*)Wco,
                          c_buf, xcat, t, sw, sb);
}

// ---------------------------------------------------------------------------
// offmod v6 (ROUND-10): output-split across TWO block types to double
// occupancy (wave starvation was the binder: 64.5 KB LDS -> 1.76 blk/CU).
// Grid 900 = 2 x 450. Type A (blk<450): outputs 0..15, LDS 36.9 KB,
// 4 og-waves x 4 outputs (1 float4/tap). Type B: outputs 16..26 (11),
// LDS 27.6 KB (12 slots, slot 11 zero-padded), 4 og x 3 outputs (b32 reads).
// 4 px/thread throughout; all weight reads wave-uniform broadcasts.
// ---------------------------------------------------------------------------
template <typename T>
__device__ __forceinline__ void offmod6_body(
    const float* __restrict__ xcat,
    const T* __restrict__ off_w, const T* __restrict__ off_b,
    const T* __restrict__ mod_w, const T* __restrict__ mod_b,
    float* __restrict__ offbuf, float* __restrict__ maskbuf,
    float* sw, float* sb)
{
    int type = (blockIdx.x >= 450) ? 1 : 0;
    int chunk = blockIdx.x - type * 450;
    const int nslot = type ? 12 : 16;

    for (int i = threadIdx.x; i < TAPS_D * nslot; i += 256) {
        int tap = i / nslot, j = i - tap * nslot;
        int o = type ? 16 + j : j;
        float v = 0.0f;
        if (o < 18) v = getv(off_w, (long)o * TAPS_D + tap);
        else if (o < 27) v = getv(mod_w, (long)(o - 18) * TAPS_D + tap);
        sw[tap * nslot + j] = v;
    }
    if (threadIdx.x < nslot) {
        int o = (type ? 16 : 0) + threadIdx.x;
        sb[threadIdx.x] = (o < 18) ? getv(off_b, o)
                        : (o < 27 ? getv(mod_b, o - 18) : 0.0f);
    }
    __syncthreads();

    int og = threadIdx.x >> 6, lane = threadIdx.x & 63;
    long p0 = ((long)chunk * 64 + lane) * 4;
    int b = (int)(p0 / HWc);
    int p = (int)(p0 - (long)b * HWc);
    int y = p / Wc, x0 = p - (p / Wc) * Wc;   // x0 % 4 == 0, in-row

    const int per = type ? 3 : 4;
    int jbase = og * per;

    float acc[4][4];
#pragma unroll
    for (int j = 0; j < 4; j++) {
        float bv = (j < per) ? sb[jbase + j] : 0.0f;
#pragma unroll
        for (int px = 0; px < 4; px++) acc[j][px] = bv;
    }

    const float* xb = xcat + (long)b * CIN_D * HWc;
    if (type == 0) {
#pragma unroll 1
        for (int cin = 0; cin < CIN_D; cin++) {
            const float* xc = xb + (long)cin * HWc;
#pragma unroll
            for (int ky = 0; ky < 3; ky++) {
                int yy = y + ky - 1;
                if (yy < 0 || yy >= Hc) continue;
                const float* row = xc + (long)yy * Wc;
                float xs[6];
                xs[0] = (x0 > 0) ? row[x0 - 1] : 0.0f;
                load4(row, x0, &xs[1]);
                xs[5] = (x0 + 4 < Wc) ? row[x0 + 4] : 0.0f;
#pragma unroll
                for (int kx = 0; kx < 3; kx++) {
                    int tap = (cin * 3 + ky) * 3 + kx;
                    const float4 wq = *(const float4*)&sw[tap * 16 + jbase];
#pragma unroll
                    for (int px = 0; px < 4; px++) {
                        float v = xs[px + kx];
                        acc[0][px] += wq.x * v;
                        acc[1][px] += wq.y * v;
                        acc[2][px] += wq.z * v;
                        acc[3][px] += wq.w * v;
                    }
                }
            }
        }
    } else {
#pragma unroll 1
        for (int cin = 0; cin < CIN_D; cin++) {
            const float* xc = xb + (long)cin * HWc;
#pragma unroll
            for (int ky = 0; ky < 3; ky++) {
                int yy = y + ky - 1;
                if (yy < 0 || yy >= Hc) continue;
                const float* row = xc + (long)yy * Wc;
                float xs[6];
                xs[0] = (x0 > 0) ? row[x0 - 1] : 0.0f;
                load4(row, x0, &xs[1]);
                xs[5] = (x0 + 4 < Wc) ? row[x0 + 4] : 0.0f;
#pragma unroll
                for (int kx = 0; kx < 3; kx++) {
                    int tap = (cin * 3 + ky) * 3 + kx;
                    const float* wp = &sw[tap * 12 + jbase];
                    float w0 = wp[0], w1 = wp[1], w2 = wp[2];
#pragma unroll
                    for (int px = 0; px < 4; px++) {
                        float v = xs[px + kx];
                        acc[0][px] += w0 * v;
                        acc[1][px] += w1 * v;
                        acc[2][px] += w2 * v;
                    }
                }
            }
        }
    }

    long pbase = (long)y * Wc + x0;
#pragma unroll
    for (int j = 0; j < 4; j++) {
        if (j >= per) break;
        int o = (type ? 16 : 0) + jbase + j;
        if (o >= 27) break;
        if (o < 18) {
            *(float4*)(offbuf + ((long)b * 18 + o) * HWc + pbase) =
                make_float4(acc[j][0], acc[j][1], acc[j][2], acc[j][3]);
        } else {
            *(float4*)(maskbuf + ((long)b * 9 + (o - 18)) * HWc + pbase) =
                make_float4(2.0f * sigm(acc[j][0]), 2.0f * sigm(acc[j][1]),
                            2.0f * sigm(acc[j][2]), 2.0f * sigm(acc[j][3]));
        }
    }
}

__global__ void __launch_bounds__(256) k_offmod(
    const float* xcat, const void* off_w, const void* off_b,
    const void* mod_w, const void* mod_b, const int* __restrict__ flag,
    float* offbuf, float* maskbuf)
{
    __shared__ float sw[TAPS_D * 16];  // 36.9 KB (type A); type B uses 27.6 KB of it
    __shared__ float sb[16];
    if (flag[0])
        offmod6_body<bf16>(xcat, (const bf16*)off_w, (const bf16*)off_b,
                           (const bf16*)mod_w, (const bf16*)mod_b, offbuf, maskbuf, sw, sb);
    else
        offmod6_body<float>(xcat, (const float*)off_w, (const float*)off_b,
                            (const float*)mod_w, (const float*)mod_b, offbuf, maskbuf, sw, sb);
}

// ---------------------------------------------------------------------------
// Deformable conv (round-3 body, unchanged).
// ---------------------------------------------------------------------------
template <typename T>
__device__ __forceinline__ void deform_body(
    const float* __restrict__ xcat, const float* __restrict__ offbuf,
    const float* __restrict__ maskbuf,
    const T* __restrict__ def_w, const T* __restrict__ def_b,
    float* __restrict__ dcout, float* sw, float* sb)
{
    for (int i = threadIdx.x; i < NKc * TAPS_D; i += 256) {
        int co = i / TAPS_D;
        int tap = i - co * TAPS_D;
        sw[tap * NKc + co] = getv(def_w, i);
    }
    if (threadIdx.x < NKc) sb[threadIdx.x] = getv(def_b, threadIdx.x);
    __syncthreads();

    int idx = blockIdx.x * 256 + threadIdx.x;
    int b = idx / HWc;
    int p = idx - b * HWc;
    int y = p / Wc, x = p - (p / Wc) * Wc;

    float acc[NKc];
#pragma unroll
    for (int i = 0; i < NKc; i++) acc[i] = 0.0f;

    const float* xb = xcat + (long)b * CIN_D * HWc;

#pragma unroll 1
    for (int k = 0; k < 9; k++) {
        int ky = k / 3, kx = k - (k / 3) * 3;
        float dy = offbuf[((long)b * 18 + 2 * k) * HWc + p];
        float dx = offbuf[((long)b * 18 + 2 * k + 1) * HWc + p];
        float m = maskbuf[((long)b * 9 + k) * HWc + p];
        float py = (float)(y - 1 + ky) + dy;
        float px = (float)(x - 1 + kx) + dx;
        float y0f = floorf(py), x0f = floorf(px);
        int y0 = (int)y0f, x0 = (int)x0f;
        float wy1 = py - y0f, wx1 = px - x0f;
        float w00 = (1.0f - wy1) * (1.0f - wx1) * m;
        float w01 = (1.0f - wy1) * wx1 * m;
        float w10 = wy1 * (1.0f - wx1) * m;
        float w11 = wy1 * wx1 * m;
        bool vy0 = (y0 >= 0) && (y0 < Hc);
        bool vy1 = (y0 + 1 >= 0) && (y0 + 1 < Hc);
        bool vx0 = (x0 >= 0) && (x0 < Wc);
        bool vx1 = (x0 + 1 >= 0) && (x0 + 1 < Wc);
        if (!(vy0 && vx0)) w00 = 0.0f;
        if (!(vy0 && vx1)) w01 = 0.0f;
        if (!(vy1 && vx0)) w10 = 0.0f;
        if (!(vy1 && vx1)) w11 = 0.0f;
        int yc0 = min(max(y0, 0), Hc - 1);
        int yc1 = min(max(y0 + 1, 0), Hc - 1);
        int xc0 = min(max(x0, 0), Wc - 1);
        int xc1 = min(max(x0 + 1, 0), Wc - 1);
        int i00 = yc0 * Wc + xc0, i01 = yc0 * Wc + xc1;
        int i10 = yc1 * Wc + xc0, i11 = yc1 * Wc + xc1;

#pragma unroll 4
        for (int cin = 0; cin < CIN_D; cin++) {
            const float* xc = xb + (long)cin * HWc;
            float s = w00 * xc[i00] + w01 * xc[i01] + w10 * xc[i10] + w11 * xc[i11];
            const float* wrow = &sw[(cin * 9 + k) * NKc];
#pragma unroll
            for (int co = 0; co < NKc; co++) acc[co] += wrow[co] * s;
        }
    }

#pragma unroll
    for (int co = 0; co < NKc; co++)
        dcout[((long)b * NKc + co) * HWc + p] = acc[co] + sb[co];
}

__global__ void __launch_bounds__(256) k_deform(
    const float* xcat, const float* offbuf, const float* maskbuf,
    const void* def_w, const void* def_b, const int* __restrict__ flag,
    float* dcout)
{
    __shared__ float sw[TAPS_D * NKc];  // 36.9 KB
    __shared__ float sb[NKc];
    if (flag[0])
        deform_body<bf16>(xcat, offbuf, maskbuf, (const bf16*)def_w, (const bf16*)def_b,
                          dcout, sw, sb);
    else
        deform_body<float>(xcat, offbuf, maskbuf, (const float*)def_w, (const float*)def_b,
                           dcout, sw, sb);
}

// ---------------------------------------------------------------------------
// outconv (R9 version, kept): 4 px/thread, 4 og x 12 outputs, hoisted rows.
// ---------------------------------------------------------------------------
template <typename T>
__device__ __forceinline__ void outconv5_body(
    const float* __restrict__ dcout, const T* __restrict__ out_w,
    const T* __restrict__ out_b, T* __restrict__ out, float* sw, float* sb)
{
    for (int i = threadIdx.x; i < 48 * TAPS_O; i += 256) {
        int co = i / TAPS_O;
        int tap = i - co * TAPS_O;
        sw[tap * 48 + co] = getv(out_w, i);
    }
    if (threadIdx.x < 48) sb[threadIdx.x] = getv(out_b, threadIdx.x);
    __syncthreads();

    int og = threadIdx.x >> 6, lane = threadIdx.x & 63;
    int obase = og * 12;
    long p0 = ((long)blockIdx.x * 64 + lane) * 4;
    int b = (int)(p0 / HWc);
    int p = (int)(p0 - (long)b * HWc);
    int y = p / Wc, x0 = p - (p / Wc) * Wc;

    float acc[12][4];
#pragma unroll
    for (int j = 0; j < 12; j++) {
        float bv = sb[obase + j];
#pragma unroll
        for (int px = 0; px < 4; px++) acc[j][px] = bv;
    }

    const float* xb = dcout + (long)b * NKc * HWc;
#pragma unroll 1
    for (int cin = 0; cin < NKc; cin++) {
        float xs[3][6];
        load_rows(xb + (long)cin * HWc, y, x0, xs);
#pragma unroll
        for (int ky = 0; ky < 3; ky++) {
#pragma unroll
            for (int kx = 0; kx < 3; kx++) {
                int tap = (cin * 3 + ky) * 3 + kx;
                const float* wp = &sw[tap * 48 + obase];
                const float4 w0 = *(const float4*)wp;
                const float4 w1 = *(const float4*)(wp + 4);
                const float4 w2 = *(const float4*)(wp + 8);
#pragma unroll
                for (int px = 0; px < 4; px++) {
                    float v = xs[ky][px + kx];
                    acc[0][px] += w0.x * v;  acc[1][px] += w0.y * v;
                    acc[2][px] += w0.z * v;  acc[3][px] += w0.w * v;
                    acc[4][px] += w1.x * v;  acc[5][px] += w1.y * v;
                    acc[6][px] += w1.z * v;  acc[7][px] += w1.w * v;
                    acc[8][px] += w2.x * v;  acc[9][px] += w2.y * v;
                    acc[10][px] += w2.z * v; acc[11][px] += w2.w * v;
                }
            }
        }
    }

#pragma unroll
    for (int j = 0; j < 12; j++) {
        int co = obase + j;
        int cc = co >> 4;
        int r = co & 15;
        int ii = r >> 2, jj = r & 3;
        long ob = (((long)b * 3 + cc) * (Hc * 4) + (y * 4 + ii)) * (long)(Wc * 4);
#pragma unroll
        for (int px = 0; px < 4; px++) {
            float v = fminf(fmaxf(acc[j][px], 0.0f), 255.0f);
            putv(out, ob + (x0 + px) * 4 + jj, v);
        }
    }
}

__global__ void __launch_bounds__(256) k_outconv(
    const float* dcout, const void* out_w, const void* out_b,
    const int* __restrict__ flag, void* out)
{
    __shared__ float sw[TAPS_O * 48];  // 27.6 KB
    __shared__ float sb[48];
    if (flag[0])
        outconv5_body<bf16>(dcout, (const bf16*)out_w, (const bf16*)out_b, (bf16*)out, sw, sb);
    else
        outconv5_body<float>(dcout, (const float*)out_w, (const float*)out_b, (float*)out, sw, sb);
}

extern "C" void kernel_launch(void* const* d_in, const int* in_sizes, int n_in,
                              void* d_out, int out_size, void* d_ws, size_t ws_size,
                              hipStream_t stream) {
    const void* X      = d_in[0];
    const void* lstm_w = d_in[1];
    const void* lstm_b = d_in[2];
    const void* Wci    = d_in[3];
    const void* Wcf    = d_in[4];
    const void* Wco    = d_in[5];
    const void* off_w  = d_in[6];
    const void* off_b  = d_in[7];
    const void* mod_w  = d_in[8];
    const void* mod_b  = d_in[9];
    const void* def_w  = d_in[10];
    const void* def_b  = d_in[11];
    const void* out_w  = d_in[12];
    const void* out_b  = d_in[13];

    int* flag = (int*)d_ws;
    float* W = (float*)d_ws + 64;
    size_t o = 0;
    float* c_buf   = W + o; o += (size_t)Bn * NKc * HWc;
    float* xcat    = W + o; o += (size_t)Bn * CIN_D * HWc;
    float* offbuf  = W + o; o += (size_t)Bn * 18 * HWc;
    float* maskbuf = W + o; o += (size_t)Bn * 9 * HWc;
    float* dcout   = W + o; o += (size_t)Bn * NKc * HWc;

    dim3 blk(256);
    dim3 gridP(NPIX / 256);          // 450
    dim3 gridL(Bn * Hc * 5);         // 1800
    dim3 gridC(NPIX / 4 / 64);       // 450
    dim3 gridC2(2 * (NPIX / 4 / 64)); // 900: output-split offmod

    k_detect<<<1, blk, 0, stream>>>(lstm_w, flag);
    for (int t = 0; t < Tn; t++) {
        k_lstm2<<<gridL, blk, 0, stream>>>(X, lstm_w, lstm_b, Wci, Wcf, Wco,
                                           flag, c_buf, xcat, t);
    }
    k_offmod<<<gridC2, blk, 0, stream>>>(xcat, off_w, off_b, mod_w, mod_b, flag,
                                         offbuf, maskbuf);
    k_deform<<<gridP, blk, 0, stream>>>(xcat, offbuf, maskbuf, def_w, def_b, flag, dcout);
    k_outconv<<<gridC, blk, 0, stream>>>(dcout, out_w, out_b, flag, d_out);
}

// Round 11
// 778.007 us; speedup vs baseline: 1.1670x; 1.0290x over previous
//
#include <hip/hip_runtime.h>
#include <hip/hip_bf16.h>

// Problem dims
#define Bn 2
#define Tn 4
#define NCc 3
#define NKc 16
#define Hc 180
#define Wc 320
#define HWc (Hc * Wc)          // 57600
#define NPIX (Bn * HWc)        // 115200
#define CIN_LSTM 19            // NC + NK
#define GATES 64               // 4*NK
#define CIN_D 64               // T*NK
#define TAPS_L (CIN_LSTM * 9)  // 171
#define TAPS_D (CIN_D * 9)     // 576
#define TAPS_O (NKc * 9)       // 144

typedef __hip_bfloat16 bf16;

__device__ __forceinline__ float getv(const float* p, long i) { return p[i]; }
__device__ __forceinline__ float getv(const bf16* p, long i) {
    unsigned int u = ((unsigned int)((const unsigned short*)p)[i]) << 16;
    return __uint_as_float(u);
}
__device__ __forceinline__ void putv(float* p, long i, float v) { p[i] = v; }
__device__ __forceinline__ void putv(bf16* p, long i, float v) { p[i] = __float2bfloat16(v); }
__device__ __forceinline__ float sigm(float x) { return 1.0f / (1.0f + __expf(-x)); }
__device__ __forceinline__ float tanh_(float x) { return 1.0f - 2.0f / (__expf(2.0f * x) + 1.0f); }

__device__ __forceinline__ void load4(const float* row, int x0, float* d) {
    const float4 v = *(const float4*)(row + x0);
    d[0] = v.x; d[1] = v.y; d[2] = v.z; d[3] = v.w;
}
__device__ __forceinline__ void load4(const bf16* row, int x0, float* d) {
    ushort4 u = *(const ushort4*)((const unsigned short*)row + x0);
    d[0] = __uint_as_float(((unsigned int)u.x) << 16);
    d[1] = __uint_as_float(((unsigned int)u.y) << 16);
    d[2] = __uint_as_float(((unsigned int)u.z) << 16);
    d[3] = __uint_as_float(((unsigned int)u.w) << 16);
}

// Hoisted 3-row window load (used by outconv): xs[ky][0..5], zeros outside.
template <typename S>
__device__ __forceinline__ void load_rows(
    const S* __restrict__ plane, int y, int x0, float (&xs)[3][6])
{
#pragma unroll
    for (int ky = 0; ky < 3; ky++) {
        int yy = y + ky - 1;
        if (yy >= 0 && yy < Hc) {
            const S* row = plane + (long)yy * Wc;
            xs[ky][0] = (x0 > 0) ? getv(row, x0 - 1) : 0.0f;
            load4(row, x0, &xs[ky][1]);
            xs[ky][5] = (x0 + 4 < Wc) ? getv(row, x0 + 4) : 0.0f;
        } else {
#pragma unroll
            for (int j = 0; j < 6; j++) xs[ky][j] = 0.0f;
        }
    }
}

// ---------------------------------------------------------------------------
// Dtype probe (bf16 vs float32 inputs) -> flag in d_ws.
// ---------------------------------------------------------------------------
__global__ void __launch_bounds__(256) k_detect(const void* lstm_w_raw, int* flag)
{
    __shared__ int bad;
    if (threadIdx.x == 0) bad = 0;
    __syncthreads();
    const unsigned short* u = (const unsigned short*)lstm_w_raw;
    int local = 0;
    for (int i = threadIdx.x; i < GATES * TAPS_L; i += 256) {
        unsigned int f32 = ((unsigned int)u[i]) << 16;
        float v = __uint_as_float(f32);
        if (!(fabsf(v) <= 64.0f)) local = 1;
    }
    if (local) atomicOr(&bad, 1);
    __syncthreads();
    if (threadIdx.x == 0) flag[0] = bad ? 0 : 1;
}

// ---------------------------------------------------------------------------
// ConvLSTM step (proven R8/R10 structure, unchanged).
// ---------------------------------------------------------------------------
template <typename S>
__device__ __forceinline__ void conv_plane(
    const S* __restrict__ src, int cin, int y, int x0, int kc,
    const float* __restrict__ sw, float (&acc)[4][4])
{
#pragma unroll
    for (int ky = 0; ky < 3; ky++) {
        int yy = y + ky - 1;
        if (yy < 0 || yy >= Hc) continue;
        const S* row = src + (long)yy * Wc;
        float xs[6];
        xs[0] = (x0 > 0) ? getv(row, x0 - 1) : 0.0f;
        load4(row, x0, &xs[1]);
        xs[5] = (x0 + 4 < Wc) ? getv(row, x0 + 4) : 0.0f;
#pragma unroll
        for (int kx = 0; kx < 3; kx++) {
            int tap = (cin * 3 + ky) * 3 + kx;
            const float4 wq = *(const float4*)&sw[(tap * 16 + kc) * 4];
#pragma unroll
            for (int px = 0; px < 4; px++) {
                float v = xs[px + kx];
                acc[0][px] += wq.x * v;
                acc[1][px] += wq.y * v;
                acc[2][px] += wq.z * v;
                acc[3][px] += wq.w * v;
            }
        }
    }
}

template <typename T>
__device__ __forceinline__ void lstm2_body(
    const T* __restrict__ X, const T* __restrict__ lstm_w, const T* __restrict__ lstm_b,
    const T* __restrict__ Wci, const T* __restrict__ Wcf, const T* __restrict__ Wco,
    float* __restrict__ c_buf, float* __restrict__ xcat, int t,
    float* sw, float* sb)
{
    for (int i = threadIdx.x; i < GATES * TAPS_L; i += 256) {
        int co = i / TAPS_L, tap = i - co * TAPS_L;
        int kc = co & 15, g = co >> 4;
        sw[(tap * 16 + kc) * 4 + g] = getv(lstm_w, i);
    }
    if (threadIdx.x < GATES) sb[threadIdx.x] = getv(lstm_b, threadIdx.x);
    __syncthreads();

    int blk = blockIdx.x;
    int seg = blk % 5; int rem = blk / 5;
    int y = rem % Hc; int b = rem / Hc;
    int kc = threadIdx.x >> 4, pl = threadIdx.x & 15;
    int x0 = seg * 64 + pl * 4;

    float acc[4][4];
#pragma unroll
    for (int px = 0; px < 4; px++) {
        acc[0][px] = sb[kc];
        acc[1][px] = sb[16 + kc];
        acc[2][px] = sb[32 + kc];
        acc[3][px] = sb[48 + kc];
    }

    const T* xt = X + (long)(b * Tn + t) * NCc * HWc;
#pragma unroll
    for (int cin = 0; cin < NCc; cin++)
        conv_plane(xt + (long)cin * HWc, cin, y, x0, kc, sw, acc);
    if (t > 0) {
        const float* hp = xcat + ((long)b * CIN_D + (t - 1) * NKc) * HWc;
#pragma unroll 1
        for (int cin = 0; cin < NKc; cin++)
            conv_plane(hp + (long)cin * HWc, cin + NCc, y, x0, kc, sw, acc);
    }

    long pbase = (long)y * Wc + x0;
    float* cb = c_buf + (long)(b * NKc + kc) * HWc + pbase;
    float cprev[4];
    if (t > 0) {
        const float4 cv = *(const float4*)cb;
        cprev[0] = cv.x; cprev[1] = cv.y; cprev[2] = cv.z; cprev[3] = cv.w;
    } else {
        cprev[0] = cprev[1] = cprev[2] = cprev[3] = 0.0f;
    }
    float wci[4], wcf[4], wco[4];
    load4(Wci + (long)kc * HWc + pbase, 0, wci);
    load4(Wcf + (long)kc * HWc + pbase, 0, wcf);
    load4(Wco + (long)kc * HWc + pbase, 0, wco);

    float cn4[4], h4[4];
#pragma unroll
    for (int px = 0; px < 4; px++) {
        float ii = sigm(acc[0][px] + wci[px] * cprev[px]);
        float ff = sigm(acc[1][px] + wcf[px] * cprev[px]);
        float cn = ff * cprev[px] + ii * tanh_(acc[2][px]);
        float oo = sigm(acc[3][px] + wco[px] * cn);
        cn4[px] = cn; h4[px] = oo * tanh_(cn);
    }
    *(float4*)cb = make_float4(cn4[0], cn4[1], cn4[2], cn4[3]);
    *(float4*)(xcat + ((long)b * CIN_D + t * NKc + kc) * HWc + pbase) =
        make_float4(h4[0], h4[1], h4[2], h4[3]);
}

__global__ void __launch_bounds__(256) k_lstm2(
    const void* X, const void* lstm_w, const void* lstm_b,
    const void* Wci, const void* Wcf, const void* Wco,
    const int* __restrict__ flag,
    float* c_buf, float* xcat, int t)
{
    __shared__ float sw[TAPS_L * GATES];  // 43.8 KB
    __shared__ float sb[GATES];
    if (flag[0])
        lstm2_body<bf16>((const bf16*)X, (const bf16*)lstm_w, (const bf16*)lstm_b,
                         (const bf16*)Wci, (const bf16*)Wcf, (const bf16*)Wco,
                         c_buf, xcat, t, sw, sb);
    else
        lstm2_body<float>((const float*)X, (const float*)lstm_w, (const float*)lstm_b,
                          (const float*)Wci, (const float*)Wcf, (const float*)Wco,
                          c_buf, xcat, t, sw, sb);
}

// ---------------------------------------------------------------------------
// offmod v6 (proven R10 output-split structure, unchanged).
// ---------------------------------------------------------------------------
template <typename T>
__device__ __forceinline__ void offmod6_body(
    const float* __restrict__ xcat,
    const T* __restrict__ off_w, const T* __restrict__ off_b,
    const T* __restrict__ mod_w, const T* __restrict__ mod_b,
    float* __restrict__ offbuf, float* __restrict__ maskbuf,
    float* sw, float* sb)
{
    int type = (blockIdx.x >= 450) ? 1 : 0;
    int chunk = blockIdx.x - type * 450;
    const int nslot = type ? 12 : 16;

    for (int i = threadIdx.x; i < TAPS_D * nslot; i += 256) {
        int tap = i / nslot, j = i - tap * nslot;
        int o = type ? 16 + j : j;
        float v = 0.0f;
        if (o < 18) v = getv(off_w, (long)o * TAPS_D + tap);
        else if (o < 27) v = getv(mod_w, (long)(o - 18) * TAPS_D + tap);
        sw[tap * nslot + j] = v;
    }
    if (threadIdx.x < nslot) {
        int o = (type ? 16 : 0) + threadIdx.x;
        sb[threadIdx.x] = (o < 18) ? getv(off_b, o)
                        : (o < 27 ? getv(mod_b, o - 18) : 0.0f);
    }
    __syncthreads();

    int og = threadIdx.x >> 6, lane = threadIdx.x & 63;
    long p0 = ((long)chunk * 64 + lane) * 4;
    int b = (int)(p0 / HWc);
    int p = (int)(p0 - (long)b * HWc);
    int y = p / Wc, x0 = p - (p / Wc) * Wc;

    const int per = type ? 3 : 4;
    int jbase = og * per;

    float acc[4][4];
#pragma unroll
    for (int j = 0; j < 4; j++) {
        float bv = (j < per) ? sb[jbase + j] : 0.0f;
#pragma unroll
        for (int px = 0; px < 4; px++) acc[j][px] = bv;
    }

    const float* xb = xcat + (long)b * CIN_D * HWc;
    if (type == 0) {
#pragma unroll 1
        for (int cin = 0; cin < CIN_D; cin++) {
            const float* xc = xb + (long)cin * HWc;
#pragma unroll
            for (int ky = 0; ky < 3; ky++) {
                int yy = y + ky - 1;
                if (yy < 0 || yy >= Hc) continue;
                const float* row = xc + (long)yy * Wc;
                float xs[6];
                xs[0] = (x0 > 0) ? row[x0 - 1] : 0.0f;
                load4(row, x0, &xs[1]);
                xs[5] = (x0 + 4 < Wc) ? row[x0 + 4] : 0.0f;
#pragma unroll
                for (int kx = 0; kx < 3; kx++) {
                    int tap = (cin * 3 + ky) * 3 + kx;
                    const float4 wq = *(const float4*)&sw[tap * 16 + jbase];
#pragma unroll
                    for (int px = 0; px < 4; px++) {
                        float v = xs[px + kx];
                        acc[0][px] += wq.x * v;
                        acc[1][px] += wq.y * v;
                        acc[2][px] += wq.z * v;
                        acc[3][px] += wq.w * v;
                    }
                }
            }
        }
    } else {
#pragma unroll 1
        for (int cin = 0; cin < CIN_D; cin++) {
            const float* xc = xb + (long)cin * HWc;
#pragma unroll
            for (int ky = 0; ky < 3; ky++) {
                int yy = y + ky - 1;
                if (yy < 0 || yy >= Hc) continue;
                const float* row = xc + (long)yy * Wc;
                float xs[6];
                xs[0] = (x0 > 0) ? row[x0 - 1] : 0.0f;
                load4(row, x0, &xs[1]);
                xs[5] = (x0 + 4 < Wc) ? row[x0 + 4] : 0.0f;
#pragma unroll
                for (int kx = 0; kx < 3; kx++) {
                    int tap = (cin * 3 + ky) * 3 + kx;
                    const float* wp = &sw[tap * 12 + jbase];
                    float w0 = wp[0], w1 = wp[1], w2 = wp[2];
#pragma unroll
                    for (int px = 0; px < 4; px++) {
                        float v = xs[px + kx];
                        acc[0][px] += w0 * v;
                        acc[1][px] += w1 * v;
                        acc[2][px] += w2 * v;
                    }
                }
            }
        }
    }

    long pbase = (long)y * Wc + x0;
#pragma unroll
    for (int j = 0; j < 4; j++) {
        if (j >= per) break;
        int o = (type ? 16 : 0) + jbase + j;
        if (o >= 27) break;
        if (o < 18) {
            *(float4*)(offbuf + ((long)b * 18 + o) * HWc + pbase) =
                make_float4(acc[j][0], acc[j][1], acc[j][2], acc[j][3]);
        } else {
            *(float4*)(maskbuf + ((long)b * 9 + (o - 18)) * HWc + pbase) =
                make_float4(2.0f * sigm(acc[j][0]), 2.0f * sigm(acc[j][1]),
                            2.0f * sigm(acc[j][2]), 2.0f * sigm(acc[j][3]));
        }
    }
}

__global__ void __launch_bounds__(256) k_offmod(
    const float* xcat, const void* off_w, const void* off_b,
    const void* mod_w, const void* mod_b, const int* __restrict__ flag,
    float* offbuf, float* maskbuf)
{
    __shared__ float sw[TAPS_D * 16];  // 36.9 KB (type A); type B uses 27.6 KB
    __shared__ float sb[16];
    if (flag[0])
        offmod6_body<bf16>(xcat, (const bf16*)off_w, (const bf16*)off_b,
                           (const bf16*)mod_w, (const bf16*)mod_b, offbuf, maskbuf, sw, sb);
    else
        offmod6_body<float>(xcat, (const float*)off_w, (const float*)off_b,
                            (const float*)mod_w, (const float*)mod_b, offbuf, maskbuf, sw, sb);
}

// ---------------------------------------------------------------------------
// deform v3 (ROUND-11): CIN-OUTER loop. Bilinear params for all 9 taps
// precomputed once into registers; per cin the 36 gathers hit one ~5 KB
// plane region (L1-resident across taps) -> kills the 9x re-walk of xcat
// that caused 373 MB FETCH. Weights LDS fp32 [tap][co] wave-uniform b128.
// ---------------------------------------------------------------------------
template <typename T>
__device__ __forceinline__ void deform3_body(
    const float* __restrict__ xcat, const float* __restrict__ offbuf,
    const float* __restrict__ maskbuf,
    const T* __restrict__ def_w, const T* __restrict__ def_b,
    float* __restrict__ dcout, float* sw, float* sb)
{
    for (int i = threadIdx.x; i < NKc * TAPS_D; i += 256) {
        int co = i / TAPS_D;
        int tap = i - co * TAPS_D;
        sw[tap * NKc + co] = getv(def_w, i);
    }
    if (threadIdx.x < NKc) sb[threadIdx.x] = getv(def_b, threadIdx.x);
    __syncthreads();

    int idx = blockIdx.x * 256 + threadIdx.x;
    int b = idx / HWc;
    int p = idx - b * HWc;
    int y = p / Wc, x = p - (p / Wc) * Wc;

    // Per-tap bilinear weights & clamped plane offsets (registers).
    float w00[9], w01[9], w10[9], w11[9];
    int i00[9], i01[9], i10[9], i11[9];
#pragma unroll
    for (int k = 0; k < 9; k++) {
        int ky = k / 3, kx = k - (k / 3) * 3;
        float dy = offbuf[((long)b * 18 + 2 * k) * HWc + p];
        float dx = offbuf[((long)b * 18 + 2 * k + 1) * HWc + p];
        float m = maskbuf[((long)b * 9 + k) * HWc + p];
        float py = (float)(y - 1 + ky) + dy;
        float px = (float)(x - 1 + kx) + dx;
        float y0f = floorf(py), x0f = floorf(px);
        int y0 = (int)y0f, x0 = (int)x0f;
        float wy1 = py - y0f, wx1 = px - x0f;
        float a00 = (1.0f - wy1) * (1.0f - wx1) * m;
        float a01 = (1.0f - wy1) * wx1 * m;
        float a10 = wy1 * (1.0f - wx1) * m;
        float a11 = wy1 * wx1 * m;
        bool vy0 = (y0 >= 0) && (y0 < Hc);
        bool vy1 = (y0 + 1 >= 0) && (y0 + 1 < Hc);
        bool vx0 = (x0 >= 0) && (x0 < Wc);
        bool vx1 = (x0 + 1 >= 0) && (x0 + 1 < Wc);
        w00[k] = (vy0 && vx0) ? a00 : 0.0f;
        w01[k] = (vy0 && vx1) ? a01 : 0.0f;
        w10[k] = (vy1 && vx0) ? a10 : 0.0f;
        w11[k] = (vy1 && vx1) ? a11 : 0.0f;
        int yc0 = min(max(y0, 0), Hc - 1);
        int yc1 = min(max(y0 + 1, 0), Hc - 1);
        int xc0 = min(max(x0, 0), Wc - 1);
        int xc1 = min(max(x0 + 1, 0), Wc - 1);
        i00[k] = yc0 * Wc + xc0; i01[k] = yc0 * Wc + xc1;
        i10[k] = yc1 * Wc + xc0; i11[k] = yc1 * Wc + xc1;
    }

    float acc[NKc];
#pragma unroll
    for (int i = 0; i < NKc; i++) acc[i] = sb[i];

    const float* xb = xcat + (long)b * CIN_D * HWc;
#pragma unroll 1
    for (int cin = 0; cin < CIN_D; cin++) {
        const float* xc = xb + (long)cin * HWc;
        float s[9];
#pragma unroll
        for (int k = 0; k < 9; k++)
            s[k] = w00[k] * xc[i00[k]] + w01[k] * xc[i01[k]] +
                   w10[k] * xc[i10[k]] + w11[k] * xc[i11[k]];
#pragma unroll
        for (int k = 0; k < 9; k++) {
            const float* wrow = &sw[(cin * 9 + k) * NKc];
#pragma unroll
            for (int co = 0; co < NKc; co++) acc[co] += wrow[co] * s[k];
        }
    }

#pragma unroll
    for (int co = 0; co < NKc; co++)
        dcout[((long)b * NKc + co) * HWc + p] = acc[co];
}

__global__ void __launch_bounds__(256) k_deform(
    const float* xcat, const float* offbuf, const float* maskbuf,
    const void* def_w, const void* def_b, const int* __restrict__ flag,
    float* dcout)
{
    __shared__ float sw[TAPS_D * NKc];  // 36.9 KB
    __shared__ float sb[NKc];
    if (flag[0])
        deform3_body<bf16>(xcat, offbuf, maskbuf, (const bf16*)def_w, (const bf16*)def_b,
                           dcout, sw, sb);
    else
        deform3_body<float>(xcat, offbuf, maskbuf, (const float*)def_w, (const float*)def_b,
                            dcout, sw, sb);
}

// ---------------------------------------------------------------------------
// outconv (proven R9/R10 version, unchanged).
// ---------------------------------------------------------------------------
template <typename T>
__device__ __forceinline__ void outconv5_body(
    const float* __restrict__ dcout, const T* __restrict__ out_w,
    const T* __restrict__ out_b, T* __restrict__ out, float* sw, float* sb)
{
    for (int i = threadIdx.x; i < 48 * TAPS_O; i += 256) {
        int co = i / TAPS_O;
        int tap = i - co * TAPS_O;
        sw[tap * 48 + co] = getv(out_w, i);
    }
    if (threadIdx.x < 48) sb[threadIdx.x] = getv(out_b, threadIdx.x);
    __syncthreads();

    int og = threadIdx.x >> 6, lane = threadIdx.x & 63;
    int obase = og * 12;
    long p0 = ((long)blockIdx.x * 64 + lane) * 4;
    int b = (int)(p0 / HWc);
    int p = (int)(p0 - (long)b * HWc);
    int y = p / Wc, x0 = p - (p / Wc) * Wc;

    float acc[12][4];
#pragma unroll
    for (int j = 0; j < 12; j++) {
        float bv = sb[obase + j];
#pragma unroll
        for (int px = 0; px < 4; px++) acc[j][px] = bv;
    }

    const float* xb = dcout + (long)b * NKc * HWc;
#pragma unroll 1
    for (int cin = 0; cin < NKc; cin++) {
        float xs[3][6];
        load_rows(xb + (long)cin * HWc, y, x0, xs);
#pragma unroll
        for (int ky = 0; ky < 3; ky++) {
#pragma unroll
            for (int kx = 0; kx < 3; kx++) {
                int tap = (cin * 3 + ky) * 3 + kx;
                const float* wp = &sw[tap * 48 + obase];
                const float4 w0 = *(const float4*)wp;
                const float4 w1 = *(const float4*)(wp + 4);
                const float4 w2 = *(const float4*)(wp + 8);
#pragma unroll
                for (int px = 0; px < 4; px++) {
                    float v = xs[ky][px + kx];
                    acc[0][px] += w0.x * v;  acc[1][px] += w0.y * v;
                    acc[2][px] += w0.z * v;  acc[3][px] += w0.w * v;
                    acc[4][px] += w1.x * v;  acc[5][px] += w1.y * v;
                    acc[6][px] += w1.z * v;  acc[7][px] += w1.w * v;
                    acc[8][px] += w2.x * v;  acc[9][px] += w2.y * v;
                    acc[10][px] += w2.z * v; acc[11][px] += w2.w * v;
                }
            }
        }
    }

#pragma unroll
    for (int j = 0; j < 12; j++) {
        int co = obase + j;
        int cc = co >> 4;
        int r = co & 15;
        int ii = r >> 2, jj = r & 3;
        long ob = (((long)b * 3 + cc) * (Hc * 4) + (y * 4 + ii)) * (long)(Wc * 4);
#pragma unroll
        for (int px = 0; px < 4; px++) {
            float v = fminf(fmaxf(acc[j][px], 0.0f), 255.0f);
            putv(out, ob + (x0 + px) * 4 + jj, v);
        }
    }
}

__global__ void __launch_bounds__(256) k_outconv(
    const float* dcout, const void* out_w, const void* out_b,
    const int* __restrict__ flag, void* out)
{
    __shared__ float sw[TAPS_O * 48];  // 27.6 KB
    __shared__ float sb[48];
    if (flag[0])
        outconv5_body<bf16>(dcout, (const bf16*)out_w, (const bf16*)out_b, (bf16*)out, sw, sb);
    else
        outconv5_body<float>(dcout, (const float*)out_w, (const float*)out_b, (float*)out, sw, sb);
}

extern "C" void kernel_launch(void* const* d_in, const int* in_sizes, int n_in,
                              void* d_out, int out_size, void* d_ws, size_t ws_size,
                              hipStream_t stream) {
    const void* X      = d_in[0];
    const void* lstm_w = d_in[1];
    const void* lstm_b = d_in[2];
    const void* Wci    = d_in[3];
    const void* Wcf    = d_in[4];
    const void* Wco    = d_in[5];
    const void* off_w  = d_in[6];
    const void* off_b  = d_in[7];
    const void* mod_w  = d_in[8];
    const void* mod_b  = d_in[9];
    const void* def_w  = d_in[10];
    const void* def_b  = d_in[11];
    const void* out_w  = d_in[12];
    const void* out_b  = d_in[13];

    int* flag = (int*)d_ws;
    float* W = (float*)d_ws + 64;
    size_t o = 0;
    float* c_buf   = W + o; o += (size_t)Bn * NKc * HWc;
    float* xcat    = W + o; o += (size_t)Bn * CIN_D * HWc;
    float* offbuf  = W + o; o += (size_t)Bn * 18 * HWc;
    float* maskbuf = W + o; o += (size_t)Bn * 9 * HWc;
    float* dcout   = W + o; o += (size_t)Bn * NKc * HWc;

    dim3 blk(256);
    dim3 gridP(NPIX / 256);           // 450
    dim3 gridL(Bn * Hc * 5);          // 1800
    dim3 gridC(NPIX / 4 / 64);        // 450
    dim3 gridC2(2 * (NPIX / 4 / 64)); // 900

    k_detect<<<1, blk, 0, stream>>>(lstm_w, flag);
    for (int t = 0; t < Tn; t++) {
        k_lstm2<<<gridL, blk, 0, stream>>>(X, lstm_w, lstm_b, Wci, Wcf, Wco,
                                           flag, c_buf, xcat, t);
    }
    k_offmod<<<gridC2, blk, 0, stream>>>(xcat, off_w, off_b, mod_w, mod_b, flag,
                                         offbuf, maskbuf);
    k_deform<<<gridP, blk, 0, stream>>>(xcat, offbuf, maskbuf, def_w, def_b, flag, dcout);
    k_outconv<<<gridC, blk, 0, stream>>>(dcout, out_w, out_b, flag, d_out);
}